// Round 1
// baseline (215.578 us; speedup 1.0000x reference)
//
#include <hip/hip_runtime.h>
#include <math.h>

// Problem constants (match reference)
constexpr int Nn   = 8192;
constexpr int Ee   = 4096;
constexpr int DIN  = 256;
constexpr int DOUT = 128;
constexpr int NNZ  = 65536;
constexpr int EC   = 96;   // capacity: nodes per edge (deg ~ Poisson(16), P(>96) ~ 0)
constexpr int NC   = 48;   // capacity: edges per node (deg ~ Poisson(8),  P(>48) ~ 0)

#define TEMPR 0.08838834764831845f   // 1/sqrt(128)
#define EM1   1.7182818284590452f    // e - 1

static __device__ __forceinline__ float wave_sum64(float v) {
#pragma unroll
    for (int m = 32; m; m >>= 1) v += __shfl_xor(v, m, 64);
    return v;
}
static __device__ __forceinline__ float wave_max64(float v) {
#pragma unroll
    for (int m = 32; m; m >>= 1) v = fmaxf(v, __shfl_xor(v, m, 64));
    return v;
}

// ---------------------------------------------------------------------------
// K1: fused GEMM  x4 = x @ W2,  xt = x @ W + bias      [8192 x 128 each, K=256]
// tile 32 rows x 128 cols, block 256 (tx=32 cols*4, ty=8 rows*4), KC=32
// ---------------------------------------------------------------------------
__global__ __launch_bounds__(256) void k_gemm1(
    const float* __restrict__ x, const float* __restrict__ W,
    const float* __restrict__ W2, const float* __restrict__ bias,
    float* __restrict__ x4, float* __restrict__ xt)
{
    __shared__ float sxT[32][36];     // [kk][row], padded
    __shared__ float swA[32][128];    // W  chunk
    __shared__ float swB[32][128];    // W2 chunk
    const int t  = threadIdx.x;
    const int tx = t & 31;
    const int ty = t >> 5;            // 0..7
    const int r0 = blockIdx.x * 32;

    float accA[4][4], accB[4][4];
#pragma unroll
    for (int r = 0; r < 4; ++r)
#pragma unroll
        for (int c = 0; c < 4; ++c) { accA[r][c] = 0.f; accB[r][c] = 0.f; }

    for (int k0 = 0; k0 < DIN; k0 += 32) {
        __syncthreads();
        {   // stage x tile (32 rows x 32 k), transposed into LDS
            const int row = t & 31;
            const int kq  = (t >> 5) * 4;
            const float4 v0 = *(const float4*)&x[(size_t)(r0 + row) * DIN + k0 + kq];
            sxT[kq + 0][row] = v0.x; sxT[kq + 1][row] = v0.y;
            sxT[kq + 2][row] = v0.z; sxT[kq + 3][row] = v0.w;
        }
#pragma unroll
        for (int i = 0; i < 4; ++i) {   // stage W / W2 chunks (32 x 128 each)
            const int idx = t + i * 256;
            const int kr  = idx >> 5;
            const int c4  = (idx & 31) * 4;
            *(float4*)&swA[kr][c4] = *(const float4*)&W [(size_t)(k0 + kr) * DOUT + c4];
            *(float4*)&swB[kr][c4] = *(const float4*)&W2[(size_t)(k0 + kr) * DOUT + c4];
        }
        __syncthreads();
#pragma unroll
        for (int kk = 0; kk < 32; ++kk) {
            const float4 a  = *(const float4*)&sxT[kk][ty * 4];
            const float4 bA = *(const float4*)&swA[kk][tx * 4];
            const float4 bB = *(const float4*)&swB[kk][tx * 4];
            const float av[4]  = {a.x,  a.y,  a.z,  a.w};
            const float bAv[4] = {bA.x, bA.y, bA.z, bA.w};
            const float bBv[4] = {bB.x, bB.y, bB.z, bB.w};
#pragma unroll
            for (int r = 0; r < 4; ++r)
#pragma unroll
                for (int c = 0; c < 4; ++c) {
                    accA[r][c] = fmaf(av[r], bAv[c], accA[r][c]);
                    accB[r][c] = fmaf(av[r], bBv[c], accB[r][c]);
                }
        }
    }
    const float4 b4 = *(const float4*)&bias[tx * 4];
#pragma unroll
    for (int r = 0; r < 4; ++r) {
        const int row = r0 + ty * 4 + r;
        float4 o;
        o.x = accB[r][0]; o.y = accB[r][1]; o.z = accB[r][2]; o.w = accB[r][3];
        *(float4*)&x4[(size_t)row * DOUT + tx * 4] = o;
        o.x = accA[r][0] + b4.x; o.y = accA[r][1] + b4.y;
        o.z = accA[r][2] + b4.z; o.w = accA[r][3] + b4.w;
        *(float4*)&xt[(size_t)row * DOUT + tx * 4] = o;
    }
}

// ---------------------------------------------------------------------------
// K2a: row[n] = dot(q_ctx, x4[n]) / TEMP      (one wave per node)
// ---------------------------------------------------------------------------
__global__ __launch_bounds__(256) void k_row(
    const float* __restrict__ x4, const float* __restrict__ q,
    float* __restrict__ rowv)
{
    const int gid  = blockIdx.x * 256 + threadIdx.x;
    const int n    = gid >> 6;
    const int lane = gid & 63;
    const float2 xv = *(const float2*)&x4[(size_t)n * DOUT + lane * 2];
    const float2 qv = *(const float2*)&q[lane * 2];
    float p = xv.x * qv.x + xv.y * qv.y;
    p = wave_sum64(p);
    if (lane == 0) rowv[n] = p * TEMPR;
}

// ---------------------------------------------------------------------------
// K2b: column sums of x4 and xt   (128 blocks x 64 rows, LDS partial + atomics)
// ---------------------------------------------------------------------------
__global__ __launch_bounds__(256) void k_colsum(
    const float* __restrict__ x4, const float* __restrict__ xt,
    float* __restrict__ csx4, float* __restrict__ csxt)
{
    __shared__ float s4[DOUT], st[DOUT];
    const int t  = threadIdx.x;
    const int tx = t & 31, ty = t >> 5;
    float4 p4 = {0,0,0,0}, pt = {0,0,0,0};
    const int n0 = blockIdx.x * 64 + ty * 8;
#pragma unroll
    for (int r = 0; r < 8; ++r) {
        const float4 a = *(const float4*)&x4[(size_t)(n0 + r) * DOUT + tx * 4];
        const float4 b = *(const float4*)&xt[(size_t)(n0 + r) * DOUT + tx * 4];
        p4.x += a.x; p4.y += a.y; p4.z += a.z; p4.w += a.w;
        pt.x += b.x; pt.y += b.y; pt.z += b.z; pt.w += b.w;
    }
    if (t < DOUT) { s4[t] = 0.f; st[t] = 0.f; }
    __syncthreads();
    atomicAdd(&s4[tx*4+0], p4.x); atomicAdd(&s4[tx*4+1], p4.y);
    atomicAdd(&s4[tx*4+2], p4.z); atomicAdd(&s4[tx*4+3], p4.w);
    atomicAdd(&st[tx*4+0], pt.x); atomicAdd(&st[tx*4+1], pt.y);
    atomicAdd(&st[tx*4+2], pt.z); atomicAdd(&st[tx*4+3], pt.w);
    __syncthreads();
    if (t < DOUT) { atomicAdd(&csx4[t], s4[t]); atomicAdd(&csxt[t], st[t]); }
}

// ---------------------------------------------------------------------------
// K3: dedup pairs via bitmap atomicOr ownership; build both CSR directions.
// ---------------------------------------------------------------------------
__global__ __launch_bounds__(256) void k_build(
    const int* __restrict__ hidx, unsigned* __restrict__ bitmap,
    int* __restrict__ degE, int* __restrict__ degN,
    int* __restrict__ csrEn, int* __restrict__ csrNe, int* __restrict__ csrNs)
{
    const int k = blockIdx.x * 256 + threadIdx.x;
    const int n = hidx[k];
    const int e = hidx[NNZ + k];
    const unsigned word = (unsigned)n * (unsigned)Ee + (unsigned)e;
    const unsigned bit  = 1u << (word & 31u);
    const unsigned old  = atomicOr(&bitmap[word >> 5], bit);
    if (!(old & bit)) {                       // this thread owns the distinct pair
        const int pe = atomicAdd(&degE[e], 1);
        if (pe < EC) {
            csrEn[e * EC + pe] = n;
            const int pn = atomicAdd(&degN[n], 1);
            if (pn < NC) {
                csrNe[n * NC + pn] = e;
                csrNs[n * NC + pn] = e * EC + pe;   // cross-link into edge-major slot
            }
        }
    }
}

// ---------------------------------------------------------------------------
// K4: per-edge softmax of scores1 over incident nodes -> Sval, plus u[e].
//     att1 = u_e * 1^T + S ;  S = (e-1)*u_e + exp(row-m)/Z at incident pairs.
// ---------------------------------------------------------------------------
__global__ __launch_bounds__(256) void k_soft1(
    const int* __restrict__ degE, const int* __restrict__ csrEn,
    const float* __restrict__ rowv, float* __restrict__ Sval,
    float* __restrict__ u)
{
    const int gid  = blockIdx.x * 256 + threadIdx.x;
    const int e    = gid >> 6;
    const int lane = gid & 63;
    const int deg  = min(degE[e], EC);
    if (deg == 0) { if (lane == 0) u[e] = 2.0f / (float)Nn; return; }
    const float ue = 1.0f / ((float)Nn + (float)deg * EM1);
    float s0 = -INFINITY, s1 = -INFINITY;
    if (lane < deg)      s0 = rowv[csrEn[e * EC + lane]];
    if (lane + 64 < deg) s1 = rowv[csrEn[e * EC + lane + 64]];
    const float m  = wave_max64(fmaxf(s0, s1));
    const float e0 = (lane < deg)      ? expf(s0 - m) : 0.f;
    const float e1 = (lane + 64 < deg) ? expf(s1 - m) : 0.f;
    const float Z  = wave_sum64(e0 + e1);
    const float inv = 1.0f / Z;
    const float base = EM1 * ue;
    if (lane < deg)      Sval[e * EC + lane]      = base + e0 * inv;
    if (lane + 64 < deg) Sval[e * EC + lane + 64] = base + e1 * inv;
    if (lane == 0) u[e] = ue;
}

// ---------------------------------------------------------------------------
// K5: per-edge gather:  edge = att1 @ xt,  G1 = att1 @ x4   (one wave / edge)
// ---------------------------------------------------------------------------
__global__ __launch_bounds__(256) void k_edgeagg(
    const int* __restrict__ degE, const int* __restrict__ csrEn,
    const float* __restrict__ Sval, const float* __restrict__ u,
    const float* __restrict__ csxt, const float* __restrict__ csx4,
    const float* __restrict__ xt, const float* __restrict__ x4,
    float* __restrict__ edgeF, float* __restrict__ G1)
{
    const int gid  = blockIdx.x * 256 + threadIdx.x;
    const int e    = gid >> 6;
    const int lane = gid & 63;
    const int deg  = min(degE[e], EC);
    const float ue = u[e];
    const float2 ct = *(const float2*)&csxt[lane * 2];
    const float2 c4 = *(const float2*)&csx4[lane * 2];
    float2 aE = make_float2(ue * ct.x, ue * ct.y);
    float2 aG = make_float2(ue * c4.x, ue * c4.y);
    for (int j = 0; j < deg; ++j) {
        const int   n = csrEn[e * EC + j];
        const float s = Sval[e * EC + j];
        const float2 tv = *(const float2*)&xt[(size_t)n * DOUT + lane * 2];
        const float2 fv = *(const float2*)&x4[(size_t)n * DOUT + lane * 2];
        aE.x = fmaf(s, tv.x, aE.x); aE.y = fmaf(s, tv.y, aE.y);
        aG.x = fmaf(s, fv.x, aG.x); aG.y = fmaf(s, fv.y, aG.y);
    }
    *(float2*)&edgeF[(size_t)e * DOUT + lane * 2] = aE;
    *(float2*)&G1  [(size_t)e * DOUT + lane * 2] = aG;
}

// ---------------------------------------------------------------------------
// K6: edge4 = edge @ W3      [4096 x 128, K=128]
// ---------------------------------------------------------------------------
__global__ __launch_bounds__(256) void k_gemm3(
    const float* __restrict__ A, const float* __restrict__ W3,
    float* __restrict__ C)
{
    __shared__ float sxT[32][36];
    __shared__ float sw[32][128];
    const int t  = threadIdx.x;
    const int tx = t & 31;
    const int ty = t >> 5;
    const int r0 = blockIdx.x * 32;
    float acc[4][4];
#pragma unroll
    for (int r = 0; r < 4; ++r)
#pragma unroll
        for (int c = 0; c < 4; ++c) acc[r][c] = 0.f;

    for (int k0 = 0; k0 < DOUT; k0 += 32) {
        __syncthreads();
        {
            const int row = t & 31;
            const int kq  = (t >> 5) * 4;
            const float4 v0 = *(const float4*)&A[(size_t)(r0 + row) * DOUT + k0 + kq];
            sxT[kq + 0][row] = v0.x; sxT[kq + 1][row] = v0.y;
            sxT[kq + 2][row] = v0.z; sxT[kq + 3][row] = v0.w;
        }
#pragma unroll
        for (int i = 0; i < 4; ++i) {
            const int idx = t + i * 256;
            const int kr  = idx >> 5;
            const int c4  = (idx & 31) * 4;
            *(float4*)&sw[kr][c4] = *(const float4*)&W3[(size_t)(k0 + kr) * DOUT + c4];
        }
        __syncthreads();
#pragma unroll
        for (int kk = 0; kk < 32; ++kk) {
            const float4 a = *(const float4*)&sxT[kk][ty * 4];
            const float4 b = *(const float4*)&sw[kk][tx * 4];
            const float av[4] = {a.x, a.y, a.z, a.w};
            const float bv[4] = {b.x, b.y, b.z, b.w};
#pragma unroll
            for (int r = 0; r < 4; ++r)
#pragma unroll
                for (int c = 0; c < 4; ++c)
                    acc[r][c] = fmaf(av[r], bv[c], acc[r][c]);
        }
    }
#pragma unroll
    for (int r = 0; r < 4; ++r) {
        const int row = r0 + ty * 4 + r;
        float4 o;
        o.x = acc[r][0]; o.y = acc[r][1]; o.z = acc[r][2]; o.w = acc[r][3];
        *(float4*)&C[(size_t)row * DOUT + tx * 4] = o;
    }
}

// ---------------------------------------------------------------------------
// K7: per-node softmax of scores2 over incident edges -> Tval (by edge-major
//     slot), plus v[n].  One wave per node; full-wave dot per incident edge.
// ---------------------------------------------------------------------------
__global__ __launch_bounds__(256) void k_soft2(
    const int* __restrict__ degN, const int* __restrict__ csrNe,
    const int* __restrict__ csrNs, const float* __restrict__ x4,
    const float* __restrict__ edge4, float* __restrict__ Tval,
    float* __restrict__ v)
{
    const int gid  = blockIdx.x * 256 + threadIdx.x;
    const int n    = gid >> 6;
    const int lane = gid & 63;
    const int deg  = min(degN[n], NC);
    if (deg == 0) { if (lane == 0) v[n] = 2.0f / (float)Ee; return; }
    const float vn = 1.0f / ((float)Ee + (float)deg * EM1);
    const float2 xv = *(const float2*)&x4[(size_t)n * DOUT + lane * 2];
    float m = -INFINITY, skeep = 0.f;
    for (int j = 0; j < deg; ++j) {        // deg <= 48 < 64
        const int e = csrNe[n * NC + j];
        const float2 ev = *(const float2*)&edge4[(size_t)e * DOUT + lane * 2];
        float s = wave_sum64(xv.x * ev.x + xv.y * ev.y) * TEMPR;
        m = fmaxf(m, s);
        if (j == lane) skeep = s;          // lane j retains s_j
    }
    const float ex = (lane < deg) ? expf(skeep - m) : 0.f;
    const float Z  = wave_sum64(ex);
    if (lane < deg) {
        const int slot = csrNs[n * NC + lane];
        Tval[slot] = EM1 * vn + ex / Z;
    }
    if (lane == 0) v[n] = vn;
}

// ---------------------------------------------------------------------------
// K8: vx[d] = sum_n v[n] * x4[n,d]
// ---------------------------------------------------------------------------
__global__ __launch_bounds__(256) void k_vx(
    const float* __restrict__ x4, const float* __restrict__ v,
    float* __restrict__ vx)
{
    __shared__ float s[DOUT];
    const int t  = threadIdx.x;
    const int tx = t & 31, ty = t >> 5;
    float4 p = {0,0,0,0};
    const int n0 = blockIdx.x * 64 + ty * 8;
#pragma unroll
    for (int r = 0; r < 8; ++r) {
        const float vn = v[n0 + r];
        const float4 a = *(const float4*)&x4[(size_t)(n0 + r) * DOUT + tx * 4];
        p.x = fmaf(vn, a.x, p.x); p.y = fmaf(vn, a.y, p.y);
        p.z = fmaf(vn, a.z, p.z); p.w = fmaf(vn, a.w, p.w);
    }
    if (t < DOUT) s[t] = 0.f;
    __syncthreads();
    atomicAdd(&s[tx*4+0], p.x); atomicAdd(&s[tx*4+1], p.y);
    atomicAdd(&s[tx*4+2], p.z); atomicAdd(&s[tx*4+3], p.w);
    __syncthreads();
    if (t < DOUT) atomicAdd(&vx[t], s[t]);
}

// ---------------------------------------------------------------------------
// K9: per-edge:  G2 = att2hn^T @ x4 ;  also accumulate w1 = sum_e u_e*G1[e,:]
//     and cg2 = sum_e G2[e,:]  (block-level LDS partials, 4 edges/block)
// ---------------------------------------------------------------------------
__global__ __launch_bounds__(256) void k_g2(
    const int* __restrict__ degE, const int* __restrict__ csrEn,
    const float* __restrict__ Tval, const float* __restrict__ u,
    const float* __restrict__ vx, const float* __restrict__ x4,
    const float* __restrict__ G1, float* __restrict__ G2,
    float* __restrict__ w1, float* __restrict__ cg2)
{
    __shared__ float sw1[DOUT], sg2[DOUT];
    const int t    = threadIdx.x;
    const int lane = t & 63;
    const int w    = t >> 6;
    if (t < DOUT) { sw1[t] = 0.f; sg2[t] = 0.f; }
    __syncthreads();
    const int e   = blockIdx.x * 4 + w;
    const int deg = min(degE[e], EC);
    float2 acc = *(const float2*)&vx[lane * 2];
    for (int j = 0; j < deg; ++j) {
        const int   n  = csrEn[e * EC + j];
        const float tv = Tval[e * EC + j];
        const float2 fv = *(const float2*)&x4[(size_t)n * DOUT + lane * 2];
        acc.x = fmaf(tv, fv.x, acc.x); acc.y = fmaf(tv, fv.y, acc.y);
    }
    *(float2*)&G2[(size_t)e * DOUT + lane * 2] = acc;
    const float  ue = u[e];
    const float2 g1 = *(const float2*)&G1[(size_t)e * DOUT + lane * 2];
    atomicAdd(&sw1[lane*2+0], ue * g1.x);
    atomicAdd(&sw1[lane*2+1], ue * g1.y);
    atomicAdd(&sg2[lane*2+0], acc.x);
    atomicAdd(&sg2[lane*2+1], acc.y);
    __syncthreads();
    if (t < DOUT) { atomicAdd(&w1[t], sw1[t]); atomicAdd(&cg2[t], sg2[t]); }
}

// ---------------------------------------------------------------------------
// K10: final per-node combine + elu:
//   out[n,:] = elu( w1 + v_n*cg2 + sum_{e in n} Sval*G1[e,:] + Tval*G2[e,:] )
// ---------------------------------------------------------------------------
__global__ __launch_bounds__(256) void k_final(
    const int* __restrict__ degN, const int* __restrict__ csrNe,
    const int* __restrict__ csrNs, const float* __restrict__ Sval,
    const float* __restrict__ Tval, const float* __restrict__ v,
    const float* __restrict__ w1, const float* __restrict__ cg2,
    const float* __restrict__ G1, const float* __restrict__ G2,
    float* __restrict__ out)
{
    const int gid  = blockIdx.x * 256 + threadIdx.x;
    const int n    = gid >> 6;
    const int lane = gid & 63;
    const int deg  = min(degN[n], NC);
    const float vn = v[n];
    const float2 wv = *(const float2*)&w1[lane * 2];
    const float2 cv = *(const float2*)&cg2[lane * 2];
    float2 acc = make_float2(fmaf(vn, cv.x, wv.x), fmaf(vn, cv.y, wv.y));
    for (int j = 0; j < deg; ++j) {
        const int e    = csrNe[n * NC + j];
        const int slot = csrNs[n * NC + j];
        const float sv = Sval[slot];
        const float tv = Tval[slot];
        const float2 g1 = *(const float2*)&G1[(size_t)e * DOUT + lane * 2];
        const float2 g2 = *(const float2*)&G2[(size_t)e * DOUT + lane * 2];
        acc.x += sv * g1.x + tv * g2.x;
        acc.y += sv * g1.y + tv * g2.y;
    }
    acc.x = acc.x > 0.f ? acc.x : expm1f(acc.x);
    acc.y = acc.y > 0.f ? acc.y : expm1f(acc.y);
    *(float2*)&out[(size_t)n * DOUT + lane * 2] = acc;
}

// ---------------------------------------------------------------------------
extern "C" void kernel_launch(void* const* d_in, const int* in_sizes, int n_in,
                              void* d_out, int out_size, void* d_ws, size_t ws_size,
                              hipStream_t stream)
{
    const float* x    = (const float*)d_in[0];
    const float* W    = (const float*)d_in[1];
    const float* W2   = (const float*)d_in[2];
    const float* W3   = (const float*)d_in[3];
    const float* bias = (const float*)d_in[4];
    const float* q    = (const float*)d_in[5];
    const int*   hidx = (const int*)d_in[6];
    float* out = (float*)d_out;

    char* ws = (char*)d_ws;
    size_t o = 0;
    auto take = [&](size_t bytes) {
        size_t r = o; o += (bytes + 255) & ~(size_t)255; return r;
    };
    // --- zero-initialized region (one memset) ---
    unsigned* bitmap = (unsigned*)(ws + take((size_t)Nn * Ee / 8));   // 4 MB
    int*   degE  = (int*)  (ws + take((size_t)Ee * 4));
    int*   degN  = (int*)  (ws + take((size_t)Nn * 4));
    float* csx4  = (float*)(ws + take(DOUT * 4));
    float* csxt  = (float*)(ws + take(DOUT * 4));
    float* vx    = (float*)(ws + take(DOUT * 4));
    float* w1    = (float*)(ws + take(DOUT * 4));
    float* cg2   = (float*)(ws + take(DOUT * 4));
    const size_t zbytes = o;
    // --- fully-overwritten scratch ---
    float* x4    = (float*)(ws + take((size_t)Nn * DOUT * 4));
    float* xt    = (float*)(ws + take((size_t)Nn * DOUT * 4));
    float* rowv  = (float*)(ws + take((size_t)Nn * 4));
    float* u     = (float*)(ws + take((size_t)Ee * 4));
    float* v     = (float*)(ws + take((size_t)Nn * 4));
    int*   csrEn = (int*)  (ws + take((size_t)Ee * EC * 4));
    float* Sval  = (float*)(ws + take((size_t)Ee * EC * 4));
    float* Tval  = (float*)(ws + take((size_t)Ee * EC * 4));
    int*   csrNe = (int*)  (ws + take((size_t)Nn * NC * 4));
    int*   csrNs = (int*)  (ws + take((size_t)Nn * NC * 4));
    float* edgeF = (float*)(ws + take((size_t)Ee * DOUT * 4));
    float* G1    = (float*)(ws + take((size_t)Ee * DOUT * 4));
    float* e4    = (float*)(ws + take((size_t)Ee * DOUT * 4));
    float* G2    = (float*)(ws + take((size_t)Ee * DOUT * 4));
    (void)ws_size; (void)in_sizes; (void)n_in; (void)out_size;

    hipMemsetAsync(d_ws, 0, zbytes, stream);

    k_gemm1  <<<Nn / 32,        256, 0, stream>>>(x, W, W2, bias, x4, xt);
    k_row    <<<Nn * 64 / 256,  256, 0, stream>>>(x4, q, rowv);
    k_colsum <<<Nn / 64,        256, 0, stream>>>(x4, xt, csx4, csxt);
    k_build  <<<NNZ / 256,      256, 0, stream>>>(hidx, bitmap, degE, degN,
                                                  csrEn, csrNe, csrNs);
    k_soft1  <<<Ee * 64 / 256,  256, 0, stream>>>(degE, csrEn, rowv, Sval, u);
    k_edgeagg<<<Ee * 64 / 256,  256, 0, stream>>>(degE, csrEn, Sval, u,
                                                  csxt, csx4, xt, x4, edgeF, G1);
    k_gemm3  <<<Ee / 32,        256, 0, stream>>>(edgeF, W3, e4);
    k_soft2  <<<Nn * 64 / 256,  256, 0, stream>>>(degN, csrNe, csrNs, x4, e4,
                                                  Tval, v);
    k_vx     <<<Nn / 64,        256, 0, stream>>>(x4, v, vx);
    k_g2     <<<Ee / 4,         256, 0, stream>>>(degE, csrEn, Tval, u, vx, x4,
                                                  G1, G2, w1, cg2);
    k_final  <<<Nn * 64 / 256,  256, 0, stream>>>(degN, csrNe, csrNs, Sval, Tval,
                                                  v, w1, cg2, G1, G2, out);
}

// Round 2
// 200.045 us; speedup vs baseline: 1.0777x; 1.0777x over previous
//
#include <hip/hip_runtime.h>
#include <math.h>

// Problem constants (match reference)
constexpr int Nn   = 8192;
constexpr int Ee   = 4096;
constexpr int DIN  = 256;
constexpr int DOUT = 128;
constexpr int NNZ  = 65536;
constexpr int EC   = 96;   // capacity: nodes per edge (deg ~ Poisson(16))
constexpr int NC   = 48;   // capacity: edges per node (deg ~ Poisson(8))

#define TEMPR 0.08838834764831845f   // 1/sqrt(128)
#define EM1   1.7182818284590452f    // e - 1

static __device__ __forceinline__ float wave_sum64(float v) {
#pragma unroll
    for (int m = 32; m; m >>= 1) v += __shfl_xor(v, m, 64);
    return v;
}
static __device__ __forceinline__ float wave_max64(float v) {
#pragma unroll
    for (int m = 32; m; m >>= 1) v = fmaxf(v, __shfl_xor(v, m, 64));
    return v;
}

// ---------------------------------------------------------------------------
// K1: fused GEMM  x4 = x @ W2,  xt = x @ W + bias   + epilogue:
//     rowv[n] = dot(q, x4[n]) * TEMPR   (in-register cross-lane reduce)
//     csx4[d] = sum_n x4[n,d], csxt[d] = sum_n xt[n,d]  (LDS + global atomics)
// ---------------------------------------------------------------------------
__global__ __launch_bounds__(256) void k_gemm1f(
    const float* __restrict__ x, const float* __restrict__ W,
    const float* __restrict__ W2, const float* __restrict__ bias,
    const float* __restrict__ q,
    float* __restrict__ x4, float* __restrict__ xt,
    float* __restrict__ rowv, float* __restrict__ csx4, float* __restrict__ csxt)
{
    __shared__ float sxT[32][36];
    __shared__ float swA[32][128];
    __shared__ float swB[32][128];
    __shared__ float s4[DOUT], st[DOUT];
    const int t  = threadIdx.x;
    const int tx = t & 31;
    const int ty = t >> 5;
    const int r0 = blockIdx.x * 32;

    float accA[4][4], accB[4][4];
#pragma unroll
    for (int r = 0; r < 4; ++r)
#pragma unroll
        for (int c = 0; c < 4; ++c) { accA[r][c] = 0.f; accB[r][c] = 0.f; }

    for (int k0 = 0; k0 < DIN; k0 += 32) {
        __syncthreads();
        {
            const int row = t & 31;
            const int kq  = (t >> 5) * 4;
            const float4 v0 = *(const float4*)&x[(size_t)(r0 + row) * DIN + k0 + kq];
            sxT[kq + 0][row] = v0.x; sxT[kq + 1][row] = v0.y;
            sxT[kq + 2][row] = v0.z; sxT[kq + 3][row] = v0.w;
        }
#pragma unroll
        for (int i = 0; i < 4; ++i) {
            const int idx = t + i * 256;
            const int kr  = idx >> 5;
            const int c4  = (idx & 31) * 4;
            *(float4*)&swA[kr][c4] = *(const float4*)&W [(size_t)(k0 + kr) * DOUT + c4];
            *(float4*)&swB[kr][c4] = *(const float4*)&W2[(size_t)(k0 + kr) * DOUT + c4];
        }
        __syncthreads();
#pragma unroll
        for (int kk = 0; kk < 32; ++kk) {
            const float4 a  = *(const float4*)&sxT[kk][ty * 4];
            const float4 bA = *(const float4*)&swA[kk][tx * 4];
            const float4 bB = *(const float4*)&swB[kk][tx * 4];
            const float av[4]  = {a.x,  a.y,  a.z,  a.w};
            const float bAv[4] = {bA.x, bA.y, bA.z, bA.w};
            const float bBv[4] = {bB.x, bB.y, bB.z, bB.w};
#pragma unroll
            for (int r = 0; r < 4; ++r)
#pragma unroll
                for (int c = 0; c < 4; ++c) {
                    accA[r][c] = fmaf(av[r], bAv[c], accA[r][c]);
                    accB[r][c] = fmaf(av[r], bBv[c], accB[r][c]);
                }
        }
    }
    const float4 b4 = *(const float4*)&bias[tx * 4];
    const float4 q4 = *(const float4*)&q[tx * 4];
#pragma unroll
    for (int r = 0; r < 4; ++r) {
        const int row = r0 + ty * 4 + r;
        float4 o;
        o.x = accB[r][0]; o.y = accB[r][1]; o.z = accB[r][2]; o.w = accB[r][3];
        *(float4*)&x4[(size_t)row * DOUT + tx * 4] = o;
        o.x = accA[r][0] + b4.x; o.y = accA[r][1] + b4.y;
        o.z = accA[r][2] + b4.z; o.w = accA[r][3] + b4.w;
        *(float4*)&xt[(size_t)row * DOUT + tx * 4] = o;
    }
    // ---- rowv: dot with q per row, reduce over tx (bits 0..4, same ty) ----
    float pr[4];
#pragma unroll
    for (int r = 0; r < 4; ++r)
        pr[r] = accB[r][0]*q4.x + accB[r][1]*q4.y + accB[r][2]*q4.z + accB[r][3]*q4.w;
#pragma unroll
    for (int m = 16; m; m >>= 1) {
#pragma unroll
        for (int r = 0; r < 4; ++r) pr[r] += __shfl_xor(pr[r], m, 64);
    }
    if (tx == 0) {
#pragma unroll
        for (int r = 0; r < 4; ++r) rowv[r0 + ty * 4 + r] = pr[r] * TEMPR;
    }
    // ---- column sums ----
    if (t < DOUT) { s4[t] = 0.f; st[t] = 0.f; }
    __syncthreads();
#pragma unroll
    for (int c = 0; c < 4; ++c) {
        float p4 = accB[0][c] + accB[1][c] + accB[2][c] + accB[3][c];
        float pt = accA[0][c] + accA[1][c] + accA[2][c] + accA[3][c]
                 + 4.f * ((const float*)&b4)[c];
        atomicAdd(&s4[tx * 4 + c], p4);
        atomicAdd(&st[tx * 4 + c], pt);
    }
    __syncthreads();
    if (t < DOUT) { atomicAdd(&csx4[t], s4[t]); atomicAdd(&csxt[t], st[t]); }
}

// ---------------------------------------------------------------------------
// K2: dedup pairs via bitmap atomicOr; build both CSR directions.
// ---------------------------------------------------------------------------
__global__ __launch_bounds__(256) void k_build(
    const int* __restrict__ hidx, unsigned* __restrict__ bitmap,
    int* __restrict__ degE, int* __restrict__ degN,
    int* __restrict__ csrEn, int* __restrict__ csrNe, int* __restrict__ csrNs)
{
    const int k = blockIdx.x * 256 + threadIdx.x;
    const int n = hidx[k];
    const int e = hidx[NNZ + k];
    const unsigned word = (unsigned)n * (unsigned)Ee + (unsigned)e;
    const unsigned bit  = 1u << (word & 31u);
    const unsigned old  = atomicOr(&bitmap[word >> 5], bit);
    if (!(old & bit)) {
        const int pe = atomicAdd(&degE[e], 1);
        if (pe < EC) {
            csrEn[e * EC + pe] = n;
            const int pn = atomicAdd(&degN[n], 1);
            if (pn < NC) {
                csrNe[n * NC + pn] = e;
                csrNs[n * NC + pn] = e * EC + pe;
            }
        }
    }
}

// ---------------------------------------------------------------------------
// K3: per-edge (1 wave/edge): softmax1 -> Sval + ws[n] scatter + c2, then
//     gather  edgeF = att1 @ xt,  G1 = att1 @ x4   (unroll-4 for MLP)
// ---------------------------------------------------------------------------
__global__ __launch_bounds__(256) void k_edge1(
    const int* __restrict__ degE, const int* __restrict__ csrEn,
    const float* __restrict__ rowv,
    const float* __restrict__ csx4, const float* __restrict__ csxt,
    const float* __restrict__ x4, const float* __restrict__ xt,
    float* __restrict__ Sval, float* __restrict__ edgeF, float* __restrict__ G1,
    float* __restrict__ wsArr, float* __restrict__ c2g)
{
    __shared__ int   sN[4][EC];
    __shared__ float sS[4][EC];
    __shared__ float sC2[4];
    const int t    = threadIdx.x;
    const int w    = t >> 6;
    const int lane = t & 63;
    const int e    = blockIdx.x * 4 + w;
    const int deg  = min(degE[e], EC);
    const float ue = deg ? 1.0f / ((float)Nn + (float)deg * EM1) : 2.0f / (float)Nn;

    int   n0 = 0, n1 = 0;
    float r0 = -INFINITY, r1 = -INFINITY;
    if (lane < deg)      { n0 = csrEn[e * EC + lane];      r0 = rowv[n0]; }
    if (lane + 64 < deg) { n1 = csrEn[e * EC + lane + 64]; r1 = rowv[n1]; }
    const float m  = wave_max64(fmaxf(r0, r1));
    const float e0 = (lane < deg)      ? expf(r0 - m) : 0.f;
    const float e1 = (lane + 64 < deg) ? expf(r1 - m) : 0.f;
    const float Z  = wave_sum64(e0 + e1);
    const float inv = (deg > 0) ? 1.0f / Z : 0.f;
    const float base = EM1 * ue;
    if (lane < deg) {
        const float sv = fmaf(e0, inv, base);
        sN[w][lane] = n0; sS[w][lane] = sv;
        Sval[e * EC + lane] = sv;
        atomicAdd(&wsArr[n0], ue * sv);
    }
    if (lane + 64 < deg) {
        const float sv = fmaf(e1, inv, base);
        sN[w][lane + 64] = n1; sS[w][lane + 64] = sv;
        Sval[e * EC + lane + 64] = sv;
        atomicAdd(&wsArr[n1], ue * sv);
    }

    const float2 ct = *(const float2*)&csxt[lane * 2];
    const float2 c4 = *(const float2*)&csx4[lane * 2];
    float2 aE = make_float2(ue * ct.x, ue * ct.y);
    float2 aG = make_float2(ue * c4.x, ue * c4.y);
    int j = 0;
    for (; j + 4 <= deg; j += 4) {
        const int a0 = sN[w][j+0], a1 = sN[w][j+1], a2 = sN[w][j+2], a3 = sN[w][j+3];
        const float b0 = sS[w][j+0], b1 = sS[w][j+1], b2 = sS[w][j+2], b3 = sS[w][j+3];
        const float2 t0 = *(const float2*)&xt[(size_t)a0 * DOUT + lane * 2];
        const float2 f0 = *(const float2*)&x4[(size_t)a0 * DOUT + lane * 2];
        const float2 t1 = *(const float2*)&xt[(size_t)a1 * DOUT + lane * 2];
        const float2 f1 = *(const float2*)&x4[(size_t)a1 * DOUT + lane * 2];
        const float2 t2 = *(const float2*)&xt[(size_t)a2 * DOUT + lane * 2];
        const float2 f2 = *(const float2*)&x4[(size_t)a2 * DOUT + lane * 2];
        const float2 t3 = *(const float2*)&xt[(size_t)a3 * DOUT + lane * 2];
        const float2 f3 = *(const float2*)&x4[(size_t)a3 * DOUT + lane * 2];
        aE.x = fmaf(b0, t0.x, aE.x); aE.y = fmaf(b0, t0.y, aE.y);
        aG.x = fmaf(b0, f0.x, aG.x); aG.y = fmaf(b0, f0.y, aG.y);
        aE.x = fmaf(b1, t1.x, aE.x); aE.y = fmaf(b1, t1.y, aE.y);
        aG.x = fmaf(b1, f1.x, aG.x); aG.y = fmaf(b1, f1.y, aG.y);
        aE.x = fmaf(b2, t2.x, aE.x); aE.y = fmaf(b2, t2.y, aE.y);
        aG.x = fmaf(b2, f2.x, aG.x); aG.y = fmaf(b2, f2.y, aG.y);
        aE.x = fmaf(b3, t3.x, aE.x); aE.y = fmaf(b3, t3.y, aE.y);
        aG.x = fmaf(b3, f3.x, aG.x); aG.y = fmaf(b3, f3.y, aG.y);
    }
    for (; j < deg; ++j) {
        const int   a = sN[w][j];
        const float b = sS[w][j];
        const float2 tv = *(const float2*)&xt[(size_t)a * DOUT + lane * 2];
        const float2 fv = *(const float2*)&x4[(size_t)a * DOUT + lane * 2];
        aE.x = fmaf(b, tv.x, aE.x); aE.y = fmaf(b, tv.y, aE.y);
        aG.x = fmaf(b, fv.x, aG.x); aG.y = fmaf(b, fv.y, aG.y);
    }
    *(float2*)&edgeF[(size_t)e * DOUT + lane * 2] = aE;
    *(float2*)&G1  [(size_t)e * DOUT + lane * 2] = aG;

    if (lane == 0) sC2[w] = ue * ue;
    __syncthreads();
    if (t == 0) atomicAdd(c2g, sC2[0] + sC2[1] + sC2[2] + sC2[3]);
}

// ---------------------------------------------------------------------------
// K4: edge4 = edgeF @ W3      [4096 x 128, K=128]
// ---------------------------------------------------------------------------
__global__ __launch_bounds__(256) void k_gemm3(
    const float* __restrict__ A, const float* __restrict__ W3,
    float* __restrict__ C)
{
    __shared__ float sxT[32][36];
    __shared__ float sw[32][128];
    const int t  = threadIdx.x;
    const int tx = t & 31;
    const int ty = t >> 5;
    const int r0 = blockIdx.x * 32;
    float acc[4][4];
#pragma unroll
    for (int r = 0; r < 4; ++r)
#pragma unroll
        for (int c = 0; c < 4; ++c) acc[r][c] = 0.f;

    for (int k0 = 0; k0 < DOUT; k0 += 32) {
        __syncthreads();
        {
            const int row = t & 31;
            const int kq  = (t >> 5) * 4;
            const float4 v0 = *(const float4*)&A[(size_t)(r0 + row) * DOUT + k0 + kq];
            sxT[kq + 0][row] = v0.x; sxT[kq + 1][row] = v0.y;
            sxT[kq + 2][row] = v0.z; sxT[kq + 3][row] = v0.w;
        }
#pragma unroll
        for (int i = 0; i < 4; ++i) {
            const int idx = t + i * 256;
            const int kr  = idx >> 5;
            const int c4  = (idx & 31) * 4;
            *(float4*)&sw[kr][c4] = *(const float4*)&W3[(size_t)(k0 + kr) * DOUT + c4];
        }
        __syncthreads();
#pragma unroll
        for (int kk = 0; kk < 32; ++kk) {
            const float4 a = *(const float4*)&sxT[kk][ty * 4];
            const float4 b = *(const float4*)&sw[kk][tx * 4];
            const float av[4] = {a.x, a.y, a.z, a.w};
            const float bv[4] = {b.x, b.y, b.z, b.w};
#pragma unroll
            for (int r = 0; r < 4; ++r)
#pragma unroll
                for (int c = 0; c < 4; ++c)
                    acc[r][c] = fmaf(av[r], bv[c], acc[r][c]);
        }
    }
#pragma unroll
    for (int r = 0; r < 4; ++r) {
        const int row = r0 + ty * 4 + r;
        float4 o;
        o.x = acc[r][0]; o.y = acc[r][1]; o.z = acc[r][2]; o.w = acc[r][3];
        *(float4*)&C[(size_t)row * DOUT + tx * 4] = o;
    }
}

// ---------------------------------------------------------------------------
// K5: per-node (16 nodes/block, 4/wave serial): softmax2 -> Tval, v[n],
//     plus weighted column-sum epilogue:
//       vx  += v_n * x4[n]          (for cg2 = Ee*vx + twx)
//       twx += tw_n * x4[n],  tw_n = deg*(e-1)*v_n + 1
//       wsx += ws[n] * x4[n]        (for w1 = c2*csx4 + wsx)
// ---------------------------------------------------------------------------
__global__ __launch_bounds__(256) void k_node2(
    const int* __restrict__ degN, const int* __restrict__ csrNe,
    const int* __restrict__ csrNs, const float* __restrict__ x4,
    const float* __restrict__ e4, const float* __restrict__ wsArr,
    float* __restrict__ Tval, float* __restrict__ vArr,
    float* __restrict__ vxg, float* __restrict__ twxg, float* __restrict__ wsxg)
{
    __shared__ float sVX[DOUT], sTX[DOUT], sWX[DOUT];
    const int t    = threadIdx.x;
    const int w    = t >> 6;
    const int lane = t & 63;
    const int nb   = blockIdx.x * 16 + w * 4;

    float2 vxa = {0,0}, twa = {0,0}, wsa = {0,0};
    for (int s = 0; s < 4; ++s) {
        const int n   = nb + s;
        const int deg = min(degN[n], NC);
        const float vn = deg ? 1.0f / ((float)Ee + (float)deg * EM1) : 2.0f / (float)Ee;
        const float2 xv = *(const float2*)&x4[(size_t)n * DOUT + lane * 2];
        float m = -INFINITY, skeep = 0.f;
        int j = 0;
        for (; j + 2 <= deg; j += 2) {
            const int ea = csrNe[n * NC + j];
            const int eb = csrNe[n * NC + j + 1];
            const float2 eva = *(const float2*)&e4[(size_t)ea * DOUT + lane * 2];
            const float2 evb = *(const float2*)&e4[(size_t)eb * DOUT + lane * 2];
            float pa = fmaf(xv.x, eva.x, xv.y * eva.y);
            float pb = fmaf(xv.x, evb.x, xv.y * evb.y);
#pragma unroll
            for (int mm = 32; mm; mm >>= 1) {
                pa += __shfl_xor(pa, mm, 64);
                pb += __shfl_xor(pb, mm, 64);
            }
            pa *= TEMPR; pb *= TEMPR;
            m = fmaxf(m, fmaxf(pa, pb));
            if (lane == j)     skeep = pa;
            if (lane == j + 1) skeep = pb;
        }
        if (j < deg) {
            const int ea = csrNe[n * NC + j];
            const float2 eva = *(const float2*)&e4[(size_t)ea * DOUT + lane * 2];
            float pa = fmaf(xv.x, eva.x, xv.y * eva.y);
            pa = wave_sum64(pa) * TEMPR;
            m = fmaxf(m, pa);
            if (lane == j) skeep = pa;
        }
        const float ex = (lane < deg) ? expf(skeep - m) : 0.f;
        const float Z  = wave_sum64(ex);
        if (lane < deg) Tval[csrNs[n * NC + lane]] = fmaf(EM1, vn, ex / Z);
        if (lane == 0) vArr[n] = vn;
        const float tw  = deg ? fmaf((float)deg * EM1, vn, 1.0f) : 0.f;
        const float wsn = wsArr[n];
        vxa.x = fmaf(vn,  xv.x, vxa.x); vxa.y = fmaf(vn,  xv.y, vxa.y);
        twa.x = fmaf(tw,  xv.x, twa.x); twa.y = fmaf(tw,  xv.y, twa.y);
        wsa.x = fmaf(wsn, xv.x, wsa.x); wsa.y = fmaf(wsn, xv.y, wsa.y);
    }
    if (t < DOUT) { sVX[t] = 0.f; sTX[t] = 0.f; sWX[t] = 0.f; }
    __syncthreads();
    atomicAdd(&sVX[lane*2+0], vxa.x); atomicAdd(&sVX[lane*2+1], vxa.y);
    atomicAdd(&sTX[lane*2+0], twa.x); atomicAdd(&sTX[lane*2+1], twa.y);
    atomicAdd(&sWX[lane*2+0], wsa.x); atomicAdd(&sWX[lane*2+1], wsa.y);
    __syncthreads();
    if (t < DOUT) {
        atomicAdd(&vxg[t],  sVX[t]);
        atomicAdd(&twxg[t], sTX[t]);
        atomicAdd(&wsxg[t], sWX[t]);
    }
}

// ---------------------------------------------------------------------------
// K6: per-edge: G2[e] = vx + sum_{n in e} T[e,n] * x4[n]   (unroll-4)
// ---------------------------------------------------------------------------
__global__ __launch_bounds__(256) void k_g2(
    const int* __restrict__ degE, const int* __restrict__ csrEn,
    const float* __restrict__ Tval, const float* __restrict__ vxg,
    const float* __restrict__ x4, float* __restrict__ G2)
{
    const int t    = threadIdx.x;
    const int w    = t >> 6;
    const int lane = t & 63;
    const int e    = blockIdx.x * 4 + w;
    const int deg  = min(degE[e], EC);
    float2 acc = *(const float2*)&vxg[lane * 2];
    int j = 0;
    for (; j + 4 <= deg; j += 4) {
        const int a0 = csrEn[e*EC+j+0], a1 = csrEn[e*EC+j+1];
        const int a2 = csrEn[e*EC+j+2], a3 = csrEn[e*EC+j+3];
        const float b0 = Tval[e*EC+j+0], b1 = Tval[e*EC+j+1];
        const float b2 = Tval[e*EC+j+2], b3 = Tval[e*EC+j+3];
        const float2 f0 = *(const float2*)&x4[(size_t)a0 * DOUT + lane * 2];
        const float2 f1 = *(const float2*)&x4[(size_t)a1 * DOUT + lane * 2];
        const float2 f2 = *(const float2*)&x4[(size_t)a2 * DOUT + lane * 2];
        const float2 f3 = *(const float2*)&x4[(size_t)a3 * DOUT + lane * 2];
        acc.x = fmaf(b0, f0.x, acc.x); acc.y = fmaf(b0, f0.y, acc.y);
        acc.x = fmaf(b1, f1.x, acc.x); acc.y = fmaf(b1, f1.y, acc.y);
        acc.x = fmaf(b2, f2.x, acc.x); acc.y = fmaf(b2, f2.y, acc.y);
        acc.x = fmaf(b3, f3.x, acc.x); acc.y = fmaf(b3, f3.y, acc.y);
    }
    for (; j < deg; ++j) {
        const int   a = csrEn[e*EC+j];
        const float b = Tval[e*EC+j];
        const float2 fv = *(const float2*)&x4[(size_t)a * DOUT + lane * 2];
        acc.x = fmaf(b, fv.x, acc.x); acc.y = fmaf(b, fv.y, acc.y);
    }
    *(float2*)&G2[(size_t)e * DOUT + lane * 2] = acc;
}

// ---------------------------------------------------------------------------
// K7: final per-node combine + elu:
//  out[n] = elu( c2*csx4 + wsx + v_n*(Ee*vx + twx) + sum_{e in n} S*G1[e] + T*G2[e] )
// ---------------------------------------------------------------------------
__global__ __launch_bounds__(256) void k_final(
    const int* __restrict__ degN, const int* __restrict__ csrNe,
    const int* __restrict__ csrNs, const float* __restrict__ Sval,
    const float* __restrict__ Tval, const float* __restrict__ vArr,
    const float* __restrict__ c2g, const float* __restrict__ csx4,
    const float* __restrict__ wsxg, const float* __restrict__ vxg,
    const float* __restrict__ twxg,
    const float* __restrict__ G1, const float* __restrict__ G2,
    float* __restrict__ out)
{
    const int t    = threadIdx.x;
    const int w    = t >> 6;
    const int lane = t & 63;
    const int n    = blockIdx.x * 4 + w;
    const int deg  = min(degN[n], NC);
    const float vn = vArr[n];
    const float c2 = *c2g;
    const float2 c4v = *(const float2*)&csx4[lane * 2];
    const float2 wsv = *(const float2*)&wsxg[lane * 2];
    const float2 vxv = *(const float2*)&vxg[lane * 2];
    const float2 twv = *(const float2*)&twxg[lane * 2];
    float2 acc;
    acc.x = fmaf(c2, c4v.x, wsv.x) + vn * fmaf((float)Ee, vxv.x, twv.x);
    acc.y = fmaf(c2, c4v.y, wsv.y) + vn * fmaf((float)Ee, vxv.y, twv.y);
    int j = 0;
    for (; j + 2 <= deg; j += 2) {
        const int ea = csrNe[n*NC+j],   eb = csrNe[n*NC+j+1];
        const int sa = csrNs[n*NC+j],   sb = csrNs[n*NC+j+1];
        const float sva = Sval[sa], tva = Tval[sa];
        const float svb = Sval[sb], tvb = Tval[sb];
        const float2 g1a = *(const float2*)&G1[(size_t)ea * DOUT + lane * 2];
        const float2 g2a = *(const float2*)&G2[(size_t)ea * DOUT + lane * 2];
        const float2 g1b = *(const float2*)&G1[(size_t)eb * DOUT + lane * 2];
        const float2 g2b = *(const float2*)&G2[(size_t)eb * DOUT + lane * 2];
        acc.x = fmaf(sva, g1a.x, acc.x); acc.y = fmaf(sva, g1a.y, acc.y);
        acc.x = fmaf(tva, g2a.x, acc.x); acc.y = fmaf(tva, g2a.y, acc.y);
        acc.x = fmaf(svb, g1b.x, acc.x); acc.y = fmaf(svb, g1b.y, acc.y);
        acc.x = fmaf(tvb, g2b.x, acc.x); acc.y = fmaf(tvb, g2b.y, acc.y);
    }
    for (; j < deg; ++j) {
        const int ea = csrNe[n*NC+j];
        const int sa = csrNs[n*NC+j];
        const float sva = Sval[sa], tva = Tval[sa];
        const float2 g1a = *(const float2*)&G1[(size_t)ea * DOUT + lane * 2];
        const float2 g2a = *(const float2*)&G2[(size_t)ea * DOUT + lane * 2];
        acc.x = fmaf(sva, g1a.x, acc.x); acc.y = fmaf(sva, g1a.y, acc.y);
        acc.x = fmaf(tva, g2a.x, acc.x); acc.y = fmaf(tva, g2a.y, acc.y);
    }
    acc.x = acc.x > 0.f ? acc.x : expm1f(acc.x);
    acc.y = acc.y > 0.f ? acc.y : expm1f(acc.y);
    *(float2*)&out[(size_t)n * DOUT + lane * 2] = acc;
}

// ---------------------------------------------------------------------------
extern "C" void kernel_launch(void* const* d_in, const int* in_sizes, int n_in,
                              void* d_out, int out_size, void* d_ws, size_t ws_size,
                              hipStream_t stream)
{
    const float* x    = (const float*)d_in[0];
    const float* W    = (const float*)d_in[1];
    const float* W2   = (const float*)d_in[2];
    const float* W3   = (const float*)d_in[3];
    const float* bias = (const float*)d_in[4];
    const float* q    = (const float*)d_in[5];
    const int*   hidx = (const int*)d_in[6];
    float* out = (float*)d_out;

    char* wsp = (char*)d_ws;
    size_t o = 0;
    auto take = [&](size_t bytes) {
        size_t r = o; o += (bytes + 255) & ~(size_t)255; return r;
    };
    // --- zero-initialized region (one memset) ---
    unsigned* bitmap = (unsigned*)(wsp + take((size_t)Nn * Ee / 8));   // 4 MB
    int*   degE  = (int*)  (wsp + take((size_t)Ee * 4));
    int*   degN  = (int*)  (wsp + take((size_t)Nn * 4));
    float* wsArr = (float*)(wsp + take((size_t)Nn * 4));
    float* c2g   = (float*)(wsp + take(4));
    float* csx4  = (float*)(wsp + take(DOUT * 4));
    float* csxt  = (float*)(wsp + take(DOUT * 4));
    float* vxg   = (float*)(wsp + take(DOUT * 4));
    float* twxg  = (float*)(wsp + take(DOUT * 4));
    float* wsxg  = (float*)(wsp + take(DOUT * 4));
    const size_t zbytes = o;
    // --- fully-overwritten scratch ---
    float* x4    = (float*)(wsp + take((size_t)Nn * DOUT * 4));
    float* xt    = (float*)(wsp + take((size_t)Nn * DOUT * 4));
    float* rowv  = (float*)(wsp + take((size_t)Nn * 4));
    float* vArr  = (float*)(wsp + take((size_t)Nn * 4));
    int*   csrEn = (int*)  (wsp + take((size_t)Ee * EC * 4));
    float* Sval  = (float*)(wsp + take((size_t)Ee * EC * 4));
    float* Tval  = (float*)(wsp + take((size_t)Ee * EC * 4));
    int*   csrNe = (int*)  (wsp + take((size_t)Nn * NC * 4));
    int*   csrNs = (int*)  (wsp + take((size_t)Nn * NC * 4));
    float* edgeF = (float*)(wsp + take((size_t)Ee * DOUT * 4));
    float* G1    = (float*)(wsp + take((size_t)Ee * DOUT * 4));
    float* e4    = (float*)(wsp + take((size_t)Ee * DOUT * 4));
    float* G2    = (float*)(wsp + take((size_t)Ee * DOUT * 4));
    (void)ws_size; (void)in_sizes; (void)n_in; (void)out_size;

    hipMemsetAsync(d_ws, 0, zbytes, stream);

    k_build <<<NNZ / 256, 256, 0, stream>>>(hidx, bitmap, degE, degN,
                                            csrEn, csrNe, csrNs);
    k_gemm1f<<<Nn / 32,   256, 0, stream>>>(x, W, W2, bias, q,
                                            x4, xt, rowv, csx4, csxt);
    k_edge1 <<<Ee / 4,    256, 0, stream>>>(degE, csrEn, rowv, csx4, csxt,
                                            x4, xt, Sval, edgeF, G1, wsArr, c2g);
    k_gemm3 <<<Ee / 32,   256, 0, stream>>>(edgeF, W3, e4);
    k_node2 <<<Nn / 16,   256, 0, stream>>>(degN, csrNe, csrNs, x4, e4, wsArr,
                                            Tval, vArr, vxg, twxg, wsxg);
    k_g2    <<<Ee / 4,    256, 0, stream>>>(degE, csrEn, Tval, vxg, x4, G2);
    k_final <<<Nn / 4,    256, 0, stream>>>(degN, csrNe, csrNs, Sval, Tval, vArr,
                                            c2g, csx4, wsxg, vxg, twxg, G1, G2, out);
}